// Round 1
// baseline (289.584 us; speedup 1.0000x reference)
//
#include <hip/hip_runtime.h>

// Problem constants (match reference)
#define BQ 512
#define AQ 32
#define DQ 256
#define NQ (BQ * AQ)      // 16384 nodes
#define EQ 1048576        // edges
#define THR 0.5f
#define EPSF 1e-5f
#define DEG_STRIDE 160    // padded bucket row; deg ~ Binom(E,1/N) mean 64, +12 sigma

typedef __attribute__((ext_vector_type(8))) short bf16x8;
typedef __attribute__((ext_vector_type(4))) float f32x4;

// fp32 -> bf16 round-to-nearest-even (finite inputs)
__device__ __forceinline__ unsigned short f2bf(float f) {
    unsigned int u = __float_as_uint(f);
    return (unsigned short)((u + 0x7FFFu + ((u >> 16) & 1u)) >> 16);
}
__device__ __forceinline__ float bf2f(unsigned short h) {
    return __uint_as_float((unsigned int)h << 16);
}

// ---------------------------------------------------------------------------
// Dispatch 1: W [K,N] fp32 -> Wt hi/lo [N,K] bf16 split (identical to the
// previous k_prep_part W-branch) + zero the per-target degree counters
// (replaces the hipMemsetAsync dispatch).
// ---------------------------------------------------------------------------
__global__ __launch_bounds__(256) void k_wt(
        const float* __restrict__ W, unsigned short* __restrict__ Wt,
        int* __restrict__ deg) {
    int tid = threadIdx.x;
    int idx = blockIdx.x * 256 + tid;       // covers DQ*DQ
    int n = idx >> 8;
    int k = idx & 255;
    float w = W[k * DQ + n];
    unsigned short h = f2bf(w);
    Wt[idx] = h;                            // hi plane
    Wt[DQ * DQ + idx] = f2bf(w - bf2f(h));  // lo plane
    if (tid < 64) deg[blockIdx.x * 64 + tid] = 0;
}

// ---------------------------------------------------------------------------
// Dispatch 2 (independent slices):
//  blocks [0,256):    direct edge scatter into per-target buckets.
//                     slot = atomicAdd(deg[t]) -> bucket[t][slot] = s.
//                     Replaces the entire bin-reservation (same-address
//                     cross-XCD atomic chains), binned round-trip, and the
//                     bucket-rebuild half-dispatch of the previous version.
//                     16K counter addresses -> ~64 atomics/address, pipelined.
//  blocks [256,512):  bf16x3 split MFMA GEMM xwb = bf16(X @ W) — code
//                     unchanged from previous version (verified rounds 5-13).
// ---------------------------------------------------------------------------
__global__ __launch_bounds__(256) void k_scatter_gemm(
        const float* __restrict__ Xp, const unsigned short* __restrict__ Wt,
        unsigned short* __restrict__ xwb,
        const int* __restrict__ src, const int* __restrict__ tgt,
        int* __restrict__ deg, unsigned short* __restrict__ bucket) {
    int tid = threadIdx.x;
    if (blockIdx.x < 256) {
        // ---- edge scatter ----
        int base = blockIdx.x * 4096;
        int t[16], s[16];
        #pragma unroll
        for (int i = 0; i < 16; i++) {
            int e = base + i * 256 + tid;
            t[i] = tgt[e];
            s[i] = src[e];
        }
        #pragma unroll
        for (int i = 0; i < 16; i++) {
            int slot = atomicAdd(&deg[t[i]], 1);
            if (slot < DEG_STRIDE)
                bucket[(size_t)t[i] * DEG_STRIDE + slot] = (unsigned short)s[i];
        }
        return;
    }
    // ---- bf16x3 split MFMA GEMM (unchanged) ----
    // A frag: A[m=lane&15][k=quad*8+j]; B frag from Wt[n][k]; C/D row=quad*4+r,
    // col=lane&15 (verified rounds 5-13).
    int wave = tid >> 6;
    int lane = tid & 63;
    int col = lane & 15;
    int quad = lane >> 4;
    int mbase = (blockIdx.x - 256) * 64 + wave * 16;
    int m = mbase + col;

    const float* arow = Xp + (size_t)m * DQ;
    const unsigned short* Wlo = Wt + DQ * DQ;

    f32x4 acc[16];
    f32x4 zero = {0.f, 0.f, 0.f, 0.f};
    #pragma unroll
    for (int i = 0; i < 16; i++) acc[i] = zero;

    for (int k0 = 0; k0 < DQ; k0 += 32) {
        int kq = k0 + quad * 8;
        float4 a0 = *(const float4*)(arow + kq);
        float4 a1 = *(const float4*)(arow + kq + 4);
        float av[8] = {a0.x, a0.y, a0.z, a0.w, a1.x, a1.y, a1.z, a1.w};
        bf16x8 ah, al;
        #pragma unroll
        for (int j = 0; j < 8; j++) {
            unsigned short h = f2bf(av[j]);
            ah[j] = (short)h;
            al[j] = (short)f2bf(av[j] - bf2f(h));
        }
        #pragma unroll
        for (int nt = 0; nt < 16; nt++) {
            size_t boff = (size_t)(nt * 16 + col) * DQ + kq;
            bf16x8 bh = *(const bf16x8*)(Wt + boff);
            bf16x8 bl = *(const bf16x8*)(Wlo + boff);
            acc[nt] = __builtin_amdgcn_mfma_f32_16x16x32_bf16(ah, bh, acc[nt], 0, 0, 0);
            acc[nt] = __builtin_amdgcn_mfma_f32_16x16x32_bf16(al, bh, acc[nt], 0, 0, 0);
            acc[nt] = __builtin_amdgcn_mfma_f32_16x16x32_bf16(ah, bl, acc[nt], 0, 0, 0);
        }
    }

    #pragma unroll
    for (int nt = 0; nt < 16; nt++) {
        #pragma unroll
        for (int r = 0; r < 4; r++) {
            xwb[(size_t)(mbase + quad * 4 + r) * DQ + nt * 16 + col] =
                f2bf(acc[nt][r]);
        }
    }
}

// ---------------------------------------------------------------------------
// Fused aggregation + scores. Grid fixed at one block per clip (512), so
// occupancy is raised by going to 1024 threads (16 waves, 2 actors/wave):
// 2 blocks/CU * 16 waves = 32 waves/CU (was 16). LDS 37.9KB*2 = 75.8KB/CU OK;
// __launch_bounds__(1024,8) pins VGPR<=64 so both blocks stay resident.
// Gather inner loop identical to the proven round-13 code; dinv is now
// computed on the fly as rsqrtf(deg+1) (bit-identical to the precomputed
// values — same rsqrtf). Score math and summation order unchanged.
// ---------------------------------------------------------------------------
__global__ __launch_bounds__(1024, 8) void k_agg_scores(
        const unsigned int* __restrict__ xwb,
        const int* __restrict__ deg,
        const unsigned short* __restrict__ bucket,
        const float* __restrict__ bias,
        float* __restrict__ out,      // Xo [NQ*DQ]
        float* __restrict__ mask) {   // [BQ*AQ*AQ]
    __shared__ float xs[AQ][DQ + 4];   // 33 KB; rows 1040B = 65x16B aligned
    __shared__ float sq[AQ];
    __shared__ float sc[AQ][AQ + 1];
    __shared__ float rmin[AQ], rmax[AQ];

    int tid = threadIdx.x;
    int wave = tid >> 6;              // 0..15
    int lane = tid & 63;
    int bq = blockIdx.x;              // batch clip
    const uint2* xw2 = (const uint2*)xwb;

    float4 bv = ((const float4*)bias)[lane];

    // ---- phase 1: gather 2 targets per wave ----
    #pragma unroll 1
    for (int i = 0; i < 2; i++) {
        int a = wave * 2 + i;         // actor 0..31
        int t = bq * AQ + a;
        int degt = deg[t];
        float dt = rsqrtf((float)(degt + 1));
        float c0 = dt * dt;
        uint2 sp = xw2[(size_t)t * 64 + lane];
        float4 acc;
        acc.x = __uint_as_float(sp.x << 16) * c0;
        acc.y = __uint_as_float(sp.x & 0xFFFF0000u) * c0;
        acc.z = __uint_as_float(sp.y << 16) * c0;
        acc.w = __uint_as_float(sp.y & 0xFFFF0000u) * c0;

        const unsigned short* brow = bucket + (size_t)t * DEG_STRIDE;
        int num = degt < DEG_STRIDE ? degt : DEG_STRIDE;
        for (int k0 = 0; k0 < num; k0 += 64) {
            int rem = num - k0;
            int n = rem < 64 ? rem : 64;
            int idx = k0 + (lane < n ? lane : 0);
            int e = (int)brow[idx];               // coalesced 2B/lane prefetch
            float cl = (lane < n) ? rsqrtf((float)(deg[e] + 1)) * dt : 0.f;
            int n8 = (n + 7) & ~7;
            for (int j0 = 0; j0 < n8; j0 += 8) {
                #pragma unroll
                for (int jj = 0; jj < 8; jj++) {
                    int j = j0 + jj;
                    int s = __shfl(e, j);
                    float c = __shfl(cl, j);
                    uint2 p = xw2[(size_t)s * 64 + lane];
                    acc.x += __uint_as_float(p.x << 16) * c;
                    acc.y += __uint_as_float(p.x & 0xFFFF0000u) * c;
                    acc.z += __uint_as_float(p.y << 16) * c;
                    acc.w += __uint_as_float(p.y & 0xFFFF0000u) * c;
                }
            }
        }

        acc.x += bv.x; acc.y += bv.y; acc.z += bv.z; acc.w += bv.w;
        ((float4*)out)[(size_t)t * 64 + lane] = acc;
        *(float4*)&xs[a][lane * 4] = acc;
    }
    __syncthreads();

    // ---- phase 2: scores (identical math / summation order) ----
    if (tid < AQ) {
        const float4* xi = (const float4*)xs[tid];
        float s = 0.f;
        #pragma unroll 8
        for (int dd = 0; dd < DQ / 4; dd++) {
            float4 a = xi[dd];
            s += a.x * a.x + a.y * a.y + a.z * a.z + a.w * a.w;
        }
        sq[tid] = s;
    }
    __syncthreads();

    {
        int i = tid >> 5;             // 1 pair per thread (1024 pairs)
        int j = tid & 31;
        const float4* xi = (const float4*)xs[i];
        const float4* xj = (const float4*)xs[j];
        float g = 0.f;
        for (int dd = 0; dd < DQ / 4; dd += 8) {
            float gq = 0.f;
            #pragma unroll
            for (int u = 0; u < 8; u++) {
                float4 a = xi[dd + u];
                float4 b = xj[dd + u];
                gq += a.x * b.x + a.y * b.y + a.z * b.z + a.w * b.w;
            }
            g += gq;
        }
        sc[i][j] = sq[i] - 2.f * g + sq[j];
    }
    __syncthreads();

    if (tid < AQ) {
        float mn = sc[tid][0], mx = sc[tid][0];
        for (int j = 1; j < AQ; j++) {
            float v = sc[tid][j];
            mn = fminf(mn, v);
            mx = fmaxf(mx, v);
        }
        rmin[tid] = mn;
        rmax[tid] = mx;
    }
    __syncthreads();

    {
        int i = tid >> 5;
        int j = tid & 31;
        float inv = 1.0f / (rmax[i] - rmin[i] + EPSF);
        mask[(size_t)bq * AQ * AQ + tid] =
            ((sc[i][j] - rmin[i]) * inv > THR) ? 1.0f : 0.0f;
    }
}

// ---------------------------------------------------------------------------
extern "C" void kernel_launch(void* const* d_in, const int* in_sizes, int n_in,
                              void* d_out, int out_size, void* d_ws, size_t ws_size,
                              hipStream_t stream) {
    const float* X    = (const float*)d_in[0];   // [B,A,D]
    const int*   ei   = (const int*)d_in[1];     // [2,E]
    const float* W    = (const float*)d_in[2];   // [D,D]
    const float* bias = (const float*)d_in[3];   // [D]
    float* out = (float*)d_out;                  // [N*D] Xo  ++  [B*A*A] mask

    char* ws = (char*)d_ws;
    unsigned short* xwb = (unsigned short*)ws;                             // 8 MB
    unsigned short* bucket = (unsigned short*)(ws + (size_t)NQ * DQ * 2);  // 5.25 MB
    unsigned short* Wt = bucket + (size_t)NQ * DEG_STRIDE;                 // 256 KB (16B-aligned)
    int* deg = (int*)(Wt + 2 * DQ * DQ);                                   // 64 KB

    const int* src = ei;
    const int* tgt = ei + EQ;

    k_wt<<<256, 256, 0, stream>>>(W, Wt, deg);
    k_scatter_gemm<<<512, 256, 0, stream>>>(X, Wt, xwb, src, tgt, deg, bucket);
    k_agg_scores<<<BQ, 1024, 0, stream>>>((const unsigned int*)xwb, deg, bucket,
                                          bias, out, out + (size_t)NQ * DQ);
}

// Round 2
// 224.300 us; speedup vs baseline: 1.2911x; 1.2911x over previous
//
#include <hip/hip_runtime.h>

// Problem constants (match reference)
#define BQ 512
#define AQ 32
#define DQ 256
#define NQ (BQ * AQ)      // 16384 nodes
#define EQ 1048576        // edges
#define THR 0.5f
#define EPSF 1e-5f
#define DEG_STRIDE 160    // padded bucket row; deg ~ Binom(E,1/N) mean 64, +12 sigma

typedef __attribute__((ext_vector_type(8))) short bf16x8;
typedef __attribute__((ext_vector_type(4))) float f32x4;

// fp32 -> bf16 round-to-nearest-even (finite inputs)
__device__ __forceinline__ unsigned short f2bf(float f) {
    unsigned int u = __float_as_uint(f);
    return (unsigned short)((u + 0x7FFFu + ((u >> 16) & 1u)) >> 16);
}
__device__ __forceinline__ float bf2f(unsigned short h) {
    return __uint_as_float((unsigned int)h << 16);
}

// ---------------------------------------------------------------------------
// Dispatch 1: W [K,N] fp32 -> Wt hi/lo [N,K] bf16 split + zero the per-target
// degree counters (replaces the hipMemsetAsync dispatch).
// ---------------------------------------------------------------------------
__global__ __launch_bounds__(256) void k_wt(
        const float* __restrict__ W, unsigned short* __restrict__ Wt,
        int* __restrict__ deg) {
    int tid = threadIdx.x;
    int idx = blockIdx.x * 256 + tid;       // covers DQ*DQ
    int n = idx >> 8;
    int k = idx & 255;
    float w = W[k * DQ + n];
    unsigned short h = f2bf(w);
    Wt[idx] = h;                            // hi plane
    Wt[DQ * DQ + idx] = f2bf(w - bf2f(h));  // lo plane
    if (tid < 64) deg[blockIdx.x * 64 + tid] = 0;
}

// ---------------------------------------------------------------------------
// Dispatch 2 (independent slices):
//  blocks [0,256):    direct edge scatter into per-target buckets.
//  blocks [256,512):  bf16x3 split MFMA GEMM xwb = bf16(X @ W) — verified
//                     rounds 5-13.
// ---------------------------------------------------------------------------
__global__ __launch_bounds__(256) void k_scatter_gemm(
        const float* __restrict__ Xp, const unsigned short* __restrict__ Wt,
        unsigned short* __restrict__ xwb,
        const int* __restrict__ src, const int* __restrict__ tgt,
        int* __restrict__ deg, unsigned short* __restrict__ bucket) {
    int tid = threadIdx.x;
    if (blockIdx.x < 256) {
        // ---- edge scatter ----
        int base = blockIdx.x * 4096;
        int t[16], s[16];
        #pragma unroll
        for (int i = 0; i < 16; i++) {
            int e = base + i * 256 + tid;
            t[i] = tgt[e];
            s[i] = src[e];
        }
        #pragma unroll
        for (int i = 0; i < 16; i++) {
            int slot = atomicAdd(&deg[t[i]], 1);
            if (slot < DEG_STRIDE)
                bucket[(size_t)t[i] * DEG_STRIDE + slot] = (unsigned short)s[i];
        }
        return;
    }
    // ---- bf16x3 split MFMA GEMM (unchanged) ----
    // A frag: A[m=lane&15][k=quad*8+j]; B frag from Wt[n][k]; C/D row=quad*4+r,
    // col=lane&15 (verified rounds 5-13).
    int wave = tid >> 6;
    int lane = tid & 63;
    int col = lane & 15;
    int quad = lane >> 4;
    int mbase = (blockIdx.x - 256) * 64 + wave * 16;
    int m = mbase + col;

    const float* arow = Xp + (size_t)m * DQ;
    const unsigned short* Wlo = Wt + DQ * DQ;

    f32x4 acc[16];
    f32x4 zero = {0.f, 0.f, 0.f, 0.f};
    #pragma unroll
    for (int i = 0; i < 16; i++) acc[i] = zero;

    for (int k0 = 0; k0 < DQ; k0 += 32) {
        int kq = k0 + quad * 8;
        float4 a0 = *(const float4*)(arow + kq);
        float4 a1 = *(const float4*)(arow + kq + 4);
        float av[8] = {a0.x, a0.y, a0.z, a0.w, a1.x, a1.y, a1.z, a1.w};
        bf16x8 ah, al;
        #pragma unroll
        for (int j = 0; j < 8; j++) {
            unsigned short h = f2bf(av[j]);
            ah[j] = (short)h;
            al[j] = (short)f2bf(av[j] - bf2f(h));
        }
        #pragma unroll
        for (int nt = 0; nt < 16; nt++) {
            size_t boff = (size_t)(nt * 16 + col) * DQ + kq;
            bf16x8 bh = *(const bf16x8*)(Wt + boff);
            bf16x8 bl = *(const bf16x8*)(Wlo + boff);
            acc[nt] = __builtin_amdgcn_mfma_f32_16x16x32_bf16(ah, bh, acc[nt], 0, 0, 0);
            acc[nt] = __builtin_amdgcn_mfma_f32_16x16x32_bf16(al, bh, acc[nt], 0, 0, 0);
            acc[nt] = __builtin_amdgcn_mfma_f32_16x16x32_bf16(ah, bl, acc[nt], 0, 0, 0);
        }
    }

    #pragma unroll
    for (int nt = 0; nt < 16; nt++) {
        #pragma unroll
        for (int r = 0; r < 4; r++) {
            xwb[(size_t)(mbase + quad * 4 + r) * DQ + nt * 16 + col] =
                f2bf(acc[nt][r]);
        }
    }
}

// ---------------------------------------------------------------------------
// Fused aggregation + scores. 1024 threads (16 waves, 2 actors/wave) to allow
// 32 waves/CU with the grid fixed at 512 blocks.
// __launch_bounds__(1024, 4): VGPR cap 128 — round-1's (1024,8) capped the
// allocator at 32 VGPRs and spilled ~380MB/dispatch to scratch (WRITE_SIZE
// 18MB->266MB). The gather body needs ~64 regs (round-0 codegen); with cap
// 128 the compiler returns to its natural allocation, and if it lands <=64
// the HW still schedules 2 blocks/CU (launch_bounds is a compiler floor,
// not an occupancy cap). Gather inner loop / score math unchanged.
// ---------------------------------------------------------------------------
__global__ __launch_bounds__(1024, 4) void k_agg_scores(
        const unsigned int* __restrict__ xwb,
        const int* __restrict__ deg,
        const unsigned short* __restrict__ bucket,
        const float* __restrict__ bias,
        float* __restrict__ out,      // Xo [NQ*DQ]
        float* __restrict__ mask) {   // [BQ*AQ*AQ]
    __shared__ float xs[AQ][DQ + 4];   // 33 KB; rows 1040B = 65x16B aligned
    __shared__ float sq[AQ];
    __shared__ float sc[AQ][AQ + 1];
    __shared__ float rmin[AQ], rmax[AQ];

    int tid = threadIdx.x;
    int wave = tid >> 6;              // 0..15
    int lane = tid & 63;
    int bq = blockIdx.x;              // batch clip
    const uint2* xw2 = (const uint2*)xwb;

    float4 bv = ((const float4*)bias)[lane];

    // ---- phase 1: gather 2 targets per wave ----
    #pragma unroll 1
    for (int i = 0; i < 2; i++) {
        int a = wave * 2 + i;         // actor 0..31
        int t = bq * AQ + a;
        int degt = deg[t];
        float dt = rsqrtf((float)(degt + 1));
        float c0 = dt * dt;
        uint2 sp = xw2[(size_t)t * 64 + lane];
        float4 acc;
        acc.x = __uint_as_float(sp.x << 16) * c0;
        acc.y = __uint_as_float(sp.x & 0xFFFF0000u) * c0;
        acc.z = __uint_as_float(sp.y << 16) * c0;
        acc.w = __uint_as_float(sp.y & 0xFFFF0000u) * c0;

        const unsigned short* brow = bucket + (size_t)t * DEG_STRIDE;
        int num = degt < DEG_STRIDE ? degt : DEG_STRIDE;
        for (int k0 = 0; k0 < num; k0 += 64) {
            int rem = num - k0;
            int n = rem < 64 ? rem : 64;
            int idx = k0 + (lane < n ? lane : 0);
            int e = (int)brow[idx];               // coalesced 2B/lane prefetch
            float cl = (lane < n) ? rsqrtf((float)(deg[e] + 1)) * dt : 0.f;
            int n8 = (n + 7) & ~7;
            for (int j0 = 0; j0 < n8; j0 += 8) {
                #pragma unroll
                for (int jj = 0; jj < 8; jj++) {
                    int j = j0 + jj;
                    int s = __shfl(e, j);
                    float c = __shfl(cl, j);
                    uint2 p = xw2[(size_t)s * 64 + lane];
                    acc.x += __uint_as_float(p.x << 16) * c;
                    acc.y += __uint_as_float(p.x & 0xFFFF0000u) * c;
                    acc.z += __uint_as_float(p.y << 16) * c;
                    acc.w += __uint_as_float(p.y & 0xFFFF0000u) * c;
                }
            }
        }

        acc.x += bv.x; acc.y += bv.y; acc.z += bv.z; acc.w += bv.w;
        ((float4*)out)[(size_t)t * 64 + lane] = acc;
        *(float4*)&xs[a][lane * 4] = acc;
    }
    __syncthreads();

    // ---- phase 2: scores (identical math / summation order) ----
    if (tid < AQ) {
        const float4* xi = (const float4*)xs[tid];
        float s = 0.f;
        #pragma unroll 8
        for (int dd = 0; dd < DQ / 4; dd++) {
            float4 a = xi[dd];
            s += a.x * a.x + a.y * a.y + a.z * a.z + a.w * a.w;
        }
        sq[tid] = s;
    }
    __syncthreads();

    {
        int i = tid >> 5;             // 1 pair per thread (1024 pairs)
        int j = tid & 31;
        const float4* xi = (const float4*)xs[i];
        const float4* xj = (const float4*)xs[j];
        float g = 0.f;
        for (int dd = 0; dd < DQ / 4; dd += 8) {
            float gq = 0.f;
            #pragma unroll
            for (int u = 0; u < 8; u++) {
                float4 a = xi[dd + u];
                float4 b = xj[dd + u];
                gq += a.x * b.x + a.y * b.y + a.z * b.z + a.w * b.w;
            }
            g += gq;
        }
        sc[i][j] = sq[i] - 2.f * g + sq[j];
    }
    __syncthreads();

    if (tid < AQ) {
        float mn = sc[tid][0], mx = sc[tid][0];
        for (int j = 1; j < AQ; j++) {
            float v = sc[tid][j];
            mn = fminf(mn, v);
            mx = fmaxf(mx, v);
        }
        rmin[tid] = mn;
        rmax[tid] = mx;
    }
    __syncthreads();

    {
        int i = tid >> 5;
        int j = tid & 31;
        float inv = 1.0f / (rmax[i] - rmin[i] + EPSF);
        mask[(size_t)bq * AQ * AQ + tid] =
            ((sc[i][j] - rmin[i]) * inv > THR) ? 1.0f : 0.0f;
    }
}

// ---------------------------------------------------------------------------
extern "C" void kernel_launch(void* const* d_in, const int* in_sizes, int n_in,
                              void* d_out, int out_size, void* d_ws, size_t ws_size,
                              hipStream_t stream) {
    const float* X    = (const float*)d_in[0];   // [B,A,D]
    const int*   ei   = (const int*)d_in[1];     // [2,E]
    const float* W    = (const float*)d_in[2];   // [D,D]
    const float* bias = (const float*)d_in[3];   // [D]
    float* out = (float*)d_out;                  // [N*D] Xo  ++  [B*A*A] mask

    char* ws = (char*)d_ws;
    unsigned short* xwb = (unsigned short*)ws;                             // 8 MB
    unsigned short* bucket = (unsigned short*)(ws + (size_t)NQ * DQ * 2);  // 5.25 MB
    unsigned short* Wt = bucket + (size_t)NQ * DEG_STRIDE;                 // 256 KB (16B-aligned)
    int* deg = (int*)(Wt + 2 * DQ * DQ);                                   // 64 KB

    const int* src = ei;
    const int* tgt = ei + EQ;

    k_wt<<<256, 256, 0, stream>>>(W, Wt, deg);
    k_scatter_gemm<<<512, 256, 0, stream>>>(X, Wt, xwb, src, tgt, deg, bucket);
    k_agg_scores<<<BQ, 1024, 0, stream>>>((const unsigned int*)xwb, deg, bucket,
                                          bias, out, out + (size_t)NQ * DQ);
}

// Round 3
// 188.978 us; speedup vs baseline: 1.5324x; 1.1869x over previous
//
#include <hip/hip_runtime.h>

// Problem constants (match reference)
#define BQ 512
#define AQ 32
#define DQ 256
#define NQ (BQ * AQ)      // 16384 nodes
#define EQ 1048576        // edges
#define THR 0.5f
#define EPSF 1e-5f
#define DEG_STRIDE 160    // per-target list cap; deg ~ Binom(E,1/N) mean 64, +12 sigma
#define BIN_TGTS 64       // targets per bin
#define NBINS (NQ / BIN_TGTS)          // 256
#define BIN_STRIDE 4864   // mean 4096 edges/bin, sigma ~64, +12 sigma

typedef __attribute__((ext_vector_type(8))) short bf16x8;
typedef __attribute__((ext_vector_type(4))) float f32x4;

// fp32 -> bf16 round-to-nearest-even (finite inputs)
__device__ __forceinline__ unsigned short f2bf(float f) {
    unsigned int u = __float_as_uint(f);
    return (unsigned short)((u + 0x7FFFu + ((u >> 16) & 1u)) >> 16);
}
__device__ __forceinline__ float bf2f(unsigned short h) {
    return __uint_as_float((unsigned int)h << 16);
}

// ---------------------------------------------------------------------------
// Dispatch 1 (EXACT round-0 code, proven):
//  blocks [0,256):    W [K,N] fp32 -> Wt hi/lo [N,K] bf16 split
//  blocks [256,512):  partition edges into 256 target-range bins, packed
//                     (t<<14|s); LDS histogram -> one global reservation per
//                     bin -> bin-grouped run-coalesced writes.
// ---------------------------------------------------------------------------
__global__ __launch_bounds__(256) void k_prep_part(
        const float* __restrict__ W, unsigned short* __restrict__ Wt,
        const int* __restrict__ src, const int* __restrict__ tgt,
        int* __restrict__ bin_cursor, unsigned int* __restrict__ binned) {
    __shared__ int hist[NBINS];
    int tid = threadIdx.x;
    if (blockIdx.x < 256) {
        int idx = blockIdx.x * 256 + tid;       // covers DQ*DQ
        int n = idx >> 8;
        int k = idx & 255;
        float w = W[k * DQ + n];
        unsigned short h = f2bf(w);
        Wt[idx] = h;                            // hi plane
        Wt[DQ * DQ + idx] = f2bf(w - bf2f(h));  // lo plane
        return;
    }
    // ---- edge partition ----
    hist[tid] = 0;
    __syncthreads();
    int base = (blockIdx.x - 256) * 4096;
    int t[16], s[16];
    #pragma unroll
    for (int i = 0; i < 16; i++) {
        int e = base + i * 256 + tid;
        t[i] = tgt[e];
        s[i] = src[e];
        atomicAdd(&hist[t[i] >> 6], 1);
    }
    __syncthreads();
    int mine = hist[tid];
    __syncthreads();
    hist[tid] = tid * BIN_STRIDE + atomicAdd(&bin_cursor[tid], mine);
    __syncthreads();
    #pragma unroll
    for (int i = 0; i < 16; i++) {
        int slot = atomicAdd(&hist[t[i] >> 6], 1);
        binned[slot] = ((unsigned int)t[i] << 14) | (unsigned int)s[i];
    }
}

// ---------------------------------------------------------------------------
// Dispatch 2:
//  blocks [0,256):    per-bin degree count -> dinv only. Replaces the round-0
//                     bucket build: no 5.25MB bucket write (k_agg now
//                     LDS-scatters its own bin half directly).
//  blocks [256,512):  bf16x3 split MFMA GEMM (EXACT round-0 code).
// ---------------------------------------------------------------------------
__global__ __launch_bounds__(256) void k_cnt_gemm(
        const float* __restrict__ Xp, const unsigned short* __restrict__ Wt,
        unsigned short* __restrict__ xwb,
        const int* __restrict__ bin_cursor, const unsigned int* __restrict__ binned,
        float* __restrict__ dinv) {
    int tid = threadIdx.x;
    if (blockIdx.x < NBINS) {
        // ---- per-bin degree count ----
        __shared__ int lcnt[BIN_TGTS];
        int b = blockIdx.x;
        if (tid < BIN_TGTS) lcnt[tid] = 0;
        __syncthreads();
        int beg = b * BIN_STRIDE;
        int count = bin_cursor[b];
        if (count > BIN_STRIDE) count = BIN_STRIDE;
        for (int i = beg + tid; i < beg + count; i += 256) {
            unsigned int ed = binned[i];
            atomicAdd(&lcnt[(ed >> 14) & 63], 1);
        }
        __syncthreads();
        if (tid < BIN_TGTS)
            dinv[b * BIN_TGTS + tid] = rsqrtf((float)(lcnt[tid] + 1));
        return;
    }
    // ---- bf16x3 split MFMA GEMM (unchanged, verified rounds 5-13) ----
    // A frag: A[m=lane&15][k=quad*8+j]; B frag from Wt[n][k]; C/D row=quad*4+r,
    // col=lane&15.
    int wave = tid >> 6;
    int lane = tid & 63;
    int col = lane & 15;
    int quad = lane >> 4;
    int mbase = (blockIdx.x - NBINS) * 64 + wave * 16;
    int m = mbase + col;

    const float* arow = Xp + (size_t)m * DQ;
    const unsigned short* Wlo = Wt + DQ * DQ;

    f32x4 acc[16];
    f32x4 zero = {0.f, 0.f, 0.f, 0.f};
    #pragma unroll
    for (int i = 0; i < 16; i++) acc[i] = zero;

    for (int k0 = 0; k0 < DQ; k0 += 32) {
        int kq = k0 + quad * 8;
        float4 a0 = *(const float4*)(arow + kq);
        float4 a1 = *(const float4*)(arow + kq + 4);
        float av[8] = {a0.x, a0.y, a0.z, a0.w, a1.x, a1.y, a1.z, a1.w};
        bf16x8 ah, al;
        #pragma unroll
        for (int j = 0; j < 8; j++) {
            unsigned short h = f2bf(av[j]);
            ah[j] = (short)h;
            al[j] = (short)f2bf(av[j] - bf2f(h));
        }
        #pragma unroll
        for (int nt = 0; nt < 16; nt++) {
            size_t boff = (size_t)(nt * 16 + col) * DQ + kq;
            bf16x8 bh = *(const bf16x8*)(Wt + boff);
            bf16x8 bl = *(const bf16x8*)(Wlo + boff);
            acc[nt] = __builtin_amdgcn_mfma_f32_16x16x32_bf16(ah, bh, acc[nt], 0, 0, 0);
            acc[nt] = __builtin_amdgcn_mfma_f32_16x16x32_bf16(al, bh, acc[nt], 0, 0, 0);
            acc[nt] = __builtin_amdgcn_mfma_f32_16x16x32_bf16(ah, bl, acc[nt], 0, 0, 0);
        }
    }

    #pragma unroll
    for (int nt = 0; nt < 16; nt++) {
        #pragma unroll
        for (int r = 0; r < 4; r++) {
            xwb[(size_t)(mbase + quad * 4 + r) * DQ + nt * 16 + col] =
                f2bf(acc[nt][r]);
        }
    }
}

// ---------------------------------------------------------------------------
// Fused aggregation + scores — round-0 proven 512-thread structure (8 waves,
// 4 actors/wave, 64 VGPR, 2 blocks/CU) with one added phase-0: LDS-scatter
// this clip's edges (half of bin bq>>1) into per-actor lists, replacing the
// global bucket reads. Gather inner loop / score math byte-identical to
// round 0.
// ---------------------------------------------------------------------------
__global__ __launch_bounds__(512) void k_agg_scores(
        const unsigned int* __restrict__ xwb,
        const unsigned int* __restrict__ binned,
        const int* __restrict__ bin_cursor,
        const float* __restrict__ dinv,
        const float* __restrict__ bias,
        float* __restrict__ out,      // Xo [NQ*DQ]
        float* __restrict__ mask) {   // [BQ*AQ*AQ]
    __shared__ float xs[AQ][DQ + 4];   // 33 KB; rows 1040B = 65x16B aligned
    __shared__ float sq[AQ];
    __shared__ float sc[AQ][AQ + 1];
    __shared__ float rmin[AQ], rmax[AQ];
    __shared__ unsigned short lbuck[AQ * DEG_STRIDE];  // 10 KB
    __shared__ int lcnt[AQ];

    int tid = threadIdx.x;
    int wave = tid >> 6;              // 0..7
    int lane = tid & 63;
    int bq = blockIdx.x;              // batch clip
    const uint2* xw2 = (const uint2*)xwb;

    // ---- phase 0: scatter this clip's edges into per-actor LDS lists ----
    if (tid < AQ) lcnt[tid] = 0;
    __syncthreads();
    {
        int b = bq >> 1;              // bin covering clips {2b, 2b+1}
        int beg = b * BIN_STRIDE;
        int count = bin_cursor[b];
        if (count > BIN_STRIDE) count = BIN_STRIDE;
        for (int i = beg + tid; i < beg + count; i += 512) {
            unsigned int ed = binned[i];
            if ((int)(ed >> 19) == bq) {          // target's clip == mine
                int a = (ed >> 14) & 31;
                int pos = atomicAdd(&lcnt[a], 1);
                if (pos < DEG_STRIDE)
                    lbuck[a * DEG_STRIDE + pos] = (unsigned short)(ed & 0x3FFFu);
            }
        }
    }
    __syncthreads();

    float4 bv = ((const float4*)bias)[lane];

    // ---- phase 1: gather 4 targets per wave (round-0 inner loop) ----
    #pragma unroll 1
    for (int i = 0; i < 4; i++) {
        int a = wave * 4 + i;         // actor 0..31
        int t = bq * AQ + a;
        float dt = dinv[t];
        float c0 = dt * dt;
        uint2 sp = xw2[(size_t)t * 64 + lane];
        float4 acc;
        acc.x = __uint_as_float(sp.x << 16) * c0;
        acc.y = __uint_as_float(sp.x & 0xFFFF0000u) * c0;
        acc.z = __uint_as_float(sp.y << 16) * c0;
        acc.w = __uint_as_float(sp.y & 0xFFFF0000u) * c0;

        int num = lcnt[a];
        if (num > DEG_STRIDE) num = DEG_STRIDE;
        for (int k0 = 0; k0 < num; k0 += 64) {
            int rem = num - k0;
            int n = rem < 64 ? rem : 64;
            int idx = k0 + (lane < n ? lane : 0);
            int e = (int)lbuck[a * DEG_STRIDE + idx];   // LDS, 2-way free
            float cl = (lane < n) ? dinv[e] * dt : 0.f;
            int n8 = (n + 7) & ~7;
            for (int j0 = 0; j0 < n8; j0 += 8) {
                #pragma unroll
                for (int jj = 0; jj < 8; jj++) {
                    int j = j0 + jj;
                    int s = __shfl(e, j);
                    float c = __shfl(cl, j);
                    uint2 p = xw2[(size_t)s * 64 + lane];
                    acc.x += __uint_as_float(p.x << 16) * c;
                    acc.y += __uint_as_float(p.x & 0xFFFF0000u) * c;
                    acc.z += __uint_as_float(p.y << 16) * c;
                    acc.w += __uint_as_float(p.y & 0xFFFF0000u) * c;
                }
            }
        }

        acc.x += bv.x; acc.y += bv.y; acc.z += bv.z; acc.w += bv.w;
        ((float4*)out)[(size_t)t * 64 + lane] = acc;
        *(float4*)&xs[a][lane * 4] = acc;
    }
    __syncthreads();

    // ---- phase 2: scores (identical math to round 0) ----
    if (tid < AQ) {
        const float4* xi = (const float4*)xs[tid];
        float s = 0.f;
        #pragma unroll 8
        for (int dd = 0; dd < DQ / 4; dd++) {
            float4 a = xi[dd];
            s += a.x * a.x + a.y * a.y + a.z * a.z + a.w * a.w;
        }
        sq[tid] = s;
    }
    __syncthreads();

    {
        int p0 = tid * 2;             // 2 pairs per thread (1024 pairs)
        int i = p0 >> 5;
        int j0 = p0 & 31;
        const float4* xi = (const float4*)xs[i];
        float g[2] = {0.f, 0.f};
        for (int dd = 0; dd < DQ / 4; dd += 8) {
            float4 ar[8];
            #pragma unroll
            for (int u = 0; u < 8; u++) ar[u] = xi[dd + u];
            #pragma unroll
            for (int q = 0; q < 2; q++) {
                const float4* xj = (const float4*)xs[j0 + q];
                float gq = 0.f;
                #pragma unroll
                for (int u = 0; u < 8; u++) {
                    float4 b = xj[dd + u];
                    gq += ar[u].x * b.x + ar[u].y * b.y +
                          ar[u].z * b.z + ar[u].w * b.w;
                }
                g[q] += gq;
            }
        }
        #pragma unroll
        for (int q = 0; q < 2; q++) {
            sc[i][j0 + q] = sq[i] - 2.f * g[q] + sq[j0 + q];
        }
    }
    __syncthreads();

    if (tid < AQ) {
        float mn = sc[tid][0], mx = sc[tid][0];
        for (int j = 1; j < AQ; j++) {
            float v = sc[tid][j];
            mn = fminf(mn, v);
            mx = fmaxf(mx, v);
        }
        rmin[tid] = mn;
        rmax[tid] = mx;
    }
    __syncthreads();

    {
        float* mb = mask + (size_t)bq * AQ * AQ;
        int p0 = tid * 2;
        int i = p0 >> 5, j0 = p0 & 31;
        float inv = 1.0f / (rmax[i] - rmin[i] + EPSF);
        float2 mv;
        mv.x = ((sc[i][j0 + 0] - rmin[i]) * inv > THR) ? 1.0f : 0.0f;
        mv.y = ((sc[i][j0 + 1] - rmin[i]) * inv > THR) ? 1.0f : 0.0f;
        ((float2*)mb)[tid] = mv;
    }
}

// ---------------------------------------------------------------------------
extern "C" void kernel_launch(void* const* d_in, const int* in_sizes, int n_in,
                              void* d_out, int out_size, void* d_ws, size_t ws_size,
                              hipStream_t stream) {
    const float* X    = (const float*)d_in[0];   // [B,A,D]
    const int*   ei   = (const int*)d_in[1];     // [2,E]
    const float* W    = (const float*)d_in[2];   // [D,D]
    const float* bias = (const float*)d_in[3];   // [D]
    float* out = (float*)d_out;                  // [N*D] Xo  ++  [B*A*A] mask

    char* ws = (char*)d_ws;
    unsigned short* xwb = (unsigned short*)ws;                              // 8 MB
    unsigned int* binned = (unsigned int*)(ws + (size_t)NQ * DQ * 2);       // 4.98 MB
    unsigned short* Wt = (unsigned short*)(binned + (size_t)NBINS * BIN_STRIDE); // 512 KB
    float* dinv = (float*)(Wt + 2 * DQ * DQ);                               // 64 KB
    int* bin_cursor = (int*)(dinv + NQ);                                    // 1 KB

    const int* src = ei;
    const int* tgt = ei + EQ;

    hipMemsetAsync(bin_cursor, 0, NBINS * sizeof(int), stream);
    k_prep_part<<<512, 256, 0, stream>>>(W, Wt, src, tgt, bin_cursor, binned);
    k_cnt_gemm<<<512, 256, 0, stream>>>(X, Wt, xwb, bin_cursor, binned, dinv);
    k_agg_scores<<<BQ, 512, 0, stream>>>((const unsigned int*)xwb, binned,
                                         bin_cursor, dinv, bias, out,
                                         out + (size_t)NQ * DQ);
}

// Round 4
// 188.007 us; speedup vs baseline: 1.5403x; 1.0052x over previous
//
#include <hip/hip_runtime.h>

// Problem constants (match reference)
#define BQ 512
#define AQ 32
#define DQ 256
#define NQ (BQ * AQ)      // 16384 nodes
#define EQ 1048576        // edges
#define THR 0.5f
#define EPSF 1e-5f
#define DEG_STRIDE 160    // per-target list cap; deg ~ Binom(E,1/N) mean 64, +12 sigma
#define BIN_TGTS 64       // targets per bin
#define NBINS (NQ / BIN_TGTS)          // 256
#define BIN_STRIDE 4864   // mean 4096 edges/bin, sigma ~64, +12 sigma

typedef __attribute__((ext_vector_type(8))) short bf16x8;
typedef __attribute__((ext_vector_type(4))) float f32x4;

// fp32 -> bf16 round-to-nearest-even (finite inputs)
__device__ __forceinline__ unsigned short f2bf(float f) {
    unsigned int u = __float_as_uint(f);
    return (unsigned short)((u + 0x7FFFu + ((u >> 16) & 1u)) >> 16);
}
__device__ __forceinline__ float bf2f(unsigned short h) {
    return __uint_as_float((unsigned int)h << 16);
}

// ---------------------------------------------------------------------------
// Dispatch 1: W [K,N] fp32 -> Wt hi/lo [N,K] bf16 split; block 0 also zeroes
// bin_cursor (absorbs the hipMemsetAsync dispatch). ~4 us.
// ---------------------------------------------------------------------------
__global__ __launch_bounds__(256) void k_wt(
        const float* __restrict__ W, unsigned short* __restrict__ Wt,
        int* __restrict__ bin_cursor) {
    int tid = threadIdx.x;
    int idx = blockIdx.x * 256 + tid;       // covers DQ*DQ
    int n = idx >> 8;
    int k = idx & 255;
    float w = W[k * DQ + n];
    unsigned short h = f2bf(w);
    Wt[idx] = h;                            // hi plane
    Wt[DQ * DQ + idx] = f2bf(w - bf2f(h));  // lo plane
    if (blockIdx.x == 0) bin_cursor[tid] = 0;   // tid < 256 == NBINS
}

// ---------------------------------------------------------------------------
// Dispatch 2 — the two HEAVY slices, overlapped (they were serialized across
// dispatches in rounds 0-3; each CU now runs ~1 partition + 1 GEMM block with
// complementary pipes: VMEM/atomics vs L1/VALU/MFMA):
//  blocks [0,256):    partition edges into 256 target-range bins (EXACT
//                     round-0/3 code): LDS histogram -> one global
//                     reservation per bin -> bin-grouped run-coalesced writes.
//  blocks [256,512):  bf16x3 split MFMA GEMM (EXACT round-0/3 code, global
//                     Wt reads — Wt ready from dispatch 1).
// ---------------------------------------------------------------------------
__global__ __launch_bounds__(256) void k_part_gemm(
        const float* __restrict__ Xp, const unsigned short* __restrict__ Wt,
        unsigned short* __restrict__ xwb,
        const int* __restrict__ src, const int* __restrict__ tgt,
        int* __restrict__ bin_cursor, unsigned int* __restrict__ binned) {
    __shared__ int hist[NBINS];
    int tid = threadIdx.x;
    if (blockIdx.x < 256) {
        // ---- edge partition ----
        hist[tid] = 0;
        __syncthreads();
        int base = blockIdx.x * 4096;
        int t[16], s[16];
        #pragma unroll
        for (int i = 0; i < 16; i++) {
            int e = base + i * 256 + tid;
            t[i] = tgt[e];
            s[i] = src[e];
            atomicAdd(&hist[t[i] >> 6], 1);
        }
        __syncthreads();
        int mine = hist[tid];
        __syncthreads();
        hist[tid] = tid * BIN_STRIDE + atomicAdd(&bin_cursor[tid], mine);
        __syncthreads();
        #pragma unroll
        for (int i = 0; i < 16; i++) {
            int slot = atomicAdd(&hist[t[i] >> 6], 1);
            binned[slot] = ((unsigned int)t[i] << 14) | (unsigned int)s[i];
        }
        return;
    }
    // ---- bf16x3 split MFMA GEMM (unchanged, verified rounds 5-13) ----
    // A frag: A[m=lane&15][k=quad*8+j]; B frag from Wt[n][k]; C/D row=quad*4+r,
    // col=lane&15.
    int wave = tid >> 6;
    int lane = tid & 63;
    int col = lane & 15;
    int quad = lane >> 4;
    int mbase = (blockIdx.x - 256) * 64 + wave * 16;
    int m = mbase + col;

    const float* arow = Xp + (size_t)m * DQ;
    const unsigned short* Wlo = Wt + DQ * DQ;

    f32x4 acc[16];
    f32x4 zero = {0.f, 0.f, 0.f, 0.f};
    #pragma unroll
    for (int i = 0; i < 16; i++) acc[i] = zero;

    for (int k0 = 0; k0 < DQ; k0 += 32) {
        int kq = k0 + quad * 8;
        float4 a0 = *(const float4*)(arow + kq);
        float4 a1 = *(const float4*)(arow + kq + 4);
        float av[8] = {a0.x, a0.y, a0.z, a0.w, a1.x, a1.y, a1.z, a1.w};
        bf16x8 ah, al;
        #pragma unroll
        for (int j = 0; j < 8; j++) {
            unsigned short h = f2bf(av[j]);
            ah[j] = (short)h;
            al[j] = (short)f2bf(av[j] - bf2f(h));
        }
        #pragma unroll
        for (int nt = 0; nt < 16; nt++) {
            size_t boff = (size_t)(nt * 16 + col) * DQ + kq;
            bf16x8 bh = *(const bf16x8*)(Wt + boff);
            bf16x8 bl = *(const bf16x8*)(Wlo + boff);
            acc[nt] = __builtin_amdgcn_mfma_f32_16x16x32_bf16(ah, bh, acc[nt], 0, 0, 0);
            acc[nt] = __builtin_amdgcn_mfma_f32_16x16x32_bf16(al, bh, acc[nt], 0, 0, 0);
            acc[nt] = __builtin_amdgcn_mfma_f32_16x16x32_bf16(ah, bl, acc[nt], 0, 0, 0);
        }
    }

    #pragma unroll
    for (int nt = 0; nt < 16; nt++) {
        #pragma unroll
        for (int r = 0; r < 4; r++) {
            xwb[(size_t)(mbase + quad * 4 + r) * DQ + nt * 16 + col] =
                f2bf(acc[nt][r]);
        }
    }
}

// ---------------------------------------------------------------------------
// Dispatch 3: per-bin degree count -> dinv (EXACT round-3 code). ~8-10 us.
// ---------------------------------------------------------------------------
__global__ __launch_bounds__(256) void k_cnt(
        const int* __restrict__ bin_cursor, const unsigned int* __restrict__ binned,
        float* __restrict__ dinv) {
    __shared__ int lcnt[BIN_TGTS];
    int tid = threadIdx.x;
    int b = blockIdx.x;
    if (tid < BIN_TGTS) lcnt[tid] = 0;
    __syncthreads();
    int beg = b * BIN_STRIDE;
    int count = bin_cursor[b];
    if (count > BIN_STRIDE) count = BIN_STRIDE;
    for (int i = beg + tid; i < beg + count; i += 256) {
        unsigned int ed = binned[i];
        atomicAdd(&lcnt[(ed >> 14) & 63], 1);
    }
    __syncthreads();
    if (tid < BIN_TGTS)
        dinv[b * BIN_TGTS + tid] = rsqrtf((float)(lcnt[tid] + 1));
}

// ---------------------------------------------------------------------------
// Fused aggregation + scores — EXACT round-3 code (512 thr, 8 waves, phase-0
// LDS scatter of this clip's half-bin, round-0 gather inner loop).
// ---------------------------------------------------------------------------
__global__ __launch_bounds__(512) void k_agg_scores(
        const unsigned int* __restrict__ xwb,
        const unsigned int* __restrict__ binned,
        const int* __restrict__ bin_cursor,
        const float* __restrict__ dinv,
        const float* __restrict__ bias,
        float* __restrict__ out,      // Xo [NQ*DQ]
        float* __restrict__ mask) {   // [BQ*AQ*AQ]
    __shared__ float xs[AQ][DQ + 4];   // 33 KB; rows 1040B = 65x16B aligned
    __shared__ float sq[AQ];
    __shared__ float sc[AQ][AQ + 1];
    __shared__ float rmin[AQ], rmax[AQ];
    __shared__ unsigned short lbuck[AQ * DEG_STRIDE];  // 10 KB
    __shared__ int lcnt[AQ];

    int tid = threadIdx.x;
    int wave = tid >> 6;              // 0..7
    int lane = tid & 63;
    int bq = blockIdx.x;              // batch clip
    const uint2* xw2 = (const uint2*)xwb;

    // ---- phase 0: scatter this clip's edges into per-actor LDS lists ----
    if (tid < AQ) lcnt[tid] = 0;
    __syncthreads();
    {
        int b = bq >> 1;              // bin covering clips {2b, 2b+1}
        int beg = b * BIN_STRIDE;
        int count = bin_cursor[b];
        if (count > BIN_STRIDE) count = BIN_STRIDE;
        for (int i = beg + tid; i < beg + count; i += 512) {
            unsigned int ed = binned[i];
            if ((int)(ed >> 19) == bq) {          // target's clip == mine
                int a = (ed >> 14) & 31;
                int pos = atomicAdd(&lcnt[a], 1);
                if (pos < DEG_STRIDE)
                    lbuck[a * DEG_STRIDE + pos] = (unsigned short)(ed & 0x3FFFu);
            }
        }
    }
    __syncthreads();

    float4 bv = ((const float4*)bias)[lane];

    // ---- phase 1: gather 4 targets per wave (round-0 inner loop) ----
    #pragma unroll 1
    for (int i = 0; i < 4; i++) {
        int a = wave * 4 + i;         // actor 0..31
        int t = bq * AQ + a;
        float dt = dinv[t];
        float c0 = dt * dt;
        uint2 sp = xw2[(size_t)t * 64 + lane];
        float4 acc;
        acc.x = __uint_as_float(sp.x << 16) * c0;
        acc.y = __uint_as_float(sp.x & 0xFFFF0000u) * c0;
        acc.z = __uint_as_float(sp.y << 16) * c0;
        acc.w = __uint_as_float(sp.y & 0xFFFF0000u) * c0;

        int num = lcnt[a];
        if (num > DEG_STRIDE) num = DEG_STRIDE;
        for (int k0 = 0; k0 < num; k0 += 64) {
            int rem = num - k0;
            int n = rem < 64 ? rem : 64;
            int idx = k0 + (lane < n ? lane : 0);
            int e = (int)lbuck[a * DEG_STRIDE + idx];   // LDS, 2-way free
            float cl = (lane < n) ? dinv[e] * dt : 0.f;
            int n8 = (n + 7) & ~7;
            for (int j0 = 0; j0 < n8; j0 += 8) {
                #pragma unroll
                for (int jj = 0; jj < 8; jj++) {
                    int j = j0 + jj;
                    int s = __shfl(e, j);
                    float c = __shfl(cl, j);
                    uint2 p = xw2[(size_t)s * 64 + lane];
                    acc.x += __uint_as_float(p.x << 16) * c;
                    acc.y += __uint_as_float(p.x & 0xFFFF0000u) * c;
                    acc.z += __uint_as_float(p.y << 16) * c;
                    acc.w += __uint_as_float(p.y & 0xFFFF0000u) * c;
                }
            }
        }

        acc.x += bv.x; acc.y += bv.y; acc.z += bv.z; acc.w += bv.w;
        ((float4*)out)[(size_t)t * 64 + lane] = acc;
        *(float4*)&xs[a][lane * 4] = acc;
    }
    __syncthreads();

    // ---- phase 2: scores (identical math to round 0) ----
    if (tid < AQ) {
        const float4* xi = (const float4*)xs[tid];
        float s = 0.f;
        #pragma unroll 8
        for (int dd = 0; dd < DQ / 4; dd++) {
            float4 a = xi[dd];
            s += a.x * a.x + a.y * a.y + a.z * a.z + a.w * a.w;
        }
        sq[tid] = s;
    }
    __syncthreads();

    {
        int p0 = tid * 2;             // 2 pairs per thread (1024 pairs)
        int i = p0 >> 5;
        int j0 = p0 & 31;
        const float4* xi = (const float4*)xs[i];
        float g[2] = {0.f, 0.f};
        for (int dd = 0; dd < DQ / 4; dd += 8) {
            float4 ar[8];
            #pragma unroll
            for (int u = 0; u < 8; u++) ar[u] = xi[dd + u];
            #pragma unroll
            for (int q = 0; q < 2; q++) {
                const float4* xj = (const float4*)xs[j0 + q];
                float gq = 0.f;
                #pragma unroll
                for (int u = 0; u < 8; u++) {
                    float4 b = xj[dd + u];
                    gq += ar[u].x * b.x + ar[u].y * b.y +
                          ar[u].z * b.z + ar[u].w * b.w;
                }
                g[q] += gq;
            }
        }
        #pragma unroll
        for (int q = 0; q < 2; q++) {
            sc[i][j0 + q] = sq[i] - 2.f * g[q] + sq[j0 + q];
        }
    }
    __syncthreads();

    if (tid < AQ) {
        float mn = sc[tid][0], mx = sc[tid][0];
        for (int j = 1; j < AQ; j++) {
            float v = sc[tid][j];
            mn = fminf(mn, v);
            mx = fmaxf(mx, v);
        }
        rmin[tid] = mn;
        rmax[tid] = mx;
    }
    __syncthreads();

    {
        float* mb = mask + (size_t)bq * AQ * AQ;
        int p0 = tid * 2;
        int i = p0 >> 5, j0 = p0 & 31;
        float inv = 1.0f / (rmax[i] - rmin[i] + EPSF);
        float2 mv;
        mv.x = ((sc[i][j0 + 0] - rmin[i]) * inv > THR) ? 1.0f : 0.0f;
        mv.y = ((sc[i][j0 + 1] - rmin[i]) * inv > THR) ? 1.0f : 0.0f;
        ((float2*)mb)[tid] = mv;
    }
}

// ---------------------------------------------------------------------------
extern "C" void kernel_launch(void* const* d_in, const int* in_sizes, int n_in,
                              void* d_out, int out_size, void* d_ws, size_t ws_size,
                              hipStream_t stream) {
    const float* X    = (const float*)d_in[0];   // [B,A,D]
    const int*   ei   = (const int*)d_in[1];     // [2,E]
    const float* W    = (const float*)d_in[2];   // [D,D]
    const float* bias = (const float*)d_in[3];   // [D]
    float* out = (float*)d_out;                  // [N*D] Xo  ++  [B*A*A] mask

    char* ws = (char*)d_ws;
    unsigned short* xwb = (unsigned short*)ws;                              // 8 MB
    unsigned int* binned = (unsigned int*)(ws + (size_t)NQ * DQ * 2);       // 4.98 MB
    unsigned short* Wt = (unsigned short*)(binned + (size_t)NBINS * BIN_STRIDE); // 256 KB
    float* dinv = (float*)(Wt + 2 * DQ * DQ);                               // 64 KB
    int* bin_cursor = (int*)(dinv + NQ);                                    // 1 KB

    const int* src = ei;
    const int* tgt = ei + EQ;

    k_wt<<<256, 256, 0, stream>>>(W, Wt, bin_cursor);
    k_part_gemm<<<512, 256, 0, stream>>>(X, Wt, xwb, src, tgt, bin_cursor, binned);
    k_cnt<<<256, 256, 0, stream>>>(bin_cursor, binned, dinv);
    k_agg_scores<<<BQ, 512, 0, stream>>>((const unsigned int*)xwb, binned,
                                         bin_cursor, dinv, bias, out,
                                         out + (size_t)NQ * DQ);
}